// Round 9
// baseline (403.604 us; speedup 1.0000x reference)
//
#include <hip/hip_runtime.h>

#define FEAT 128
#define SLABS 4

typedef __attribute__((ext_vector_type(8))) _Float16 f16x8;
typedef __attribute__((ext_vector_type(2))) _Float16 f16x2;
typedef __attribute__((ext_vector_type(4))) float f32x4;

static __device__ __forceinline__ int wave_incl_scan(int v, int lane) {
#pragma unroll
    for (int off = 1; off < 64; off <<= 1) {
        int u = __shfl_up(v, off, 64);
        if (lane >= off) v += u;
    }
    return v;
}

// ---------------------------------------------------------------------------
// Prep: histogram over (dst,slab) keys + weight/bias/feat converts, one
// dispatch partitioned by blockIdx (all three parts independent).
// ---------------------------------------------------------------------------

__global__ void prep_kernel(const int* __restrict__ src, const int* __restrict__ dst,
                            int* __restrict__ deg4, int E, int slab_size,
                            const float* __restrict__ tw, const float* __restrict__ pw,
                            const float* __restrict__ tb, const float* __restrict__ pb,
                            _Float16* __restrict__ wt, _Float16* __restrict__ wp,
                            float* __restrict__ bsum, int wn, int nbias,
                            const float* __restrict__ x, _Float16* __restrict__ x16, int xn4,
                            int hb, int wb) {
    int bid = blockIdx.x;
    if (bid < hb) {
        int e = bid * 256 + threadIdx.x;
        if (e < E) {
            int sl = src[e] / slab_size;
            atomicAdd(&deg4[dst[e] * SLABS + sl], 1);
        }
    } else if (bid < hb + wb) {
        int i = (bid - hb) * 256 + threadIdx.x;
        if (i < wn) { wt[i] = (_Float16)tw[i]; wp[i] = (_Float16)pw[i]; }
        if (i < nbias) bsum[i] = tb[i] + pb[i];
    } else {
        int i = (bid - hb - wb) * 256 + threadIdx.x;
        if (i < xn4) {
            float4 v = ((const float4*)x)[i];
            f16x2 a, b;
            a[0] = (_Float16)v.x; a[1] = (_Float16)v.y;
            b[0] = (_Float16)v.z; b[1] = (_Float16)v.w;
            ((f16x2*)x16)[i * 2] = a;
            ((f16x2*)x16)[i * 2 + 1] = b;
        }
    }
}

// ---------------------------------------------------------------------------
// 3-phase parallel scan over the 4N (dst,slab) degree array.
// ---------------------------------------------------------------------------

__global__ __launch_bounds__(1024) void scan1_kernel(const int* __restrict__ deg,
                                                     int* __restrict__ row_ptr,
                                                     int* __restrict__ bsum, int N4) {
    int i = blockIdx.x * 1024 + threadIdx.x;
    int lane = threadIdx.x & 63;
    int w = threadIdx.x >> 6;
    int v = (i < N4) ? deg[i] : 0;
    int inc = wave_incl_scan(v, lane);
    __shared__ int wsum[16];
    if (lane == 63) wsum[w] = inc;
    __syncthreads();
    if (w == 0) {
        int s = (lane < 16) ? wsum[lane] : 0;
        int si = wave_incl_scan(s, lane);
        if (lane < 16) wsum[lane] = si - s;
    }
    __syncthreads();
    int exc = inc - v + wsum[w];
    if (i < N4) row_ptr[i] = exc;
    if (threadIdx.x == 1023) bsum[blockIdx.x] = exc + v;
}

__global__ __launch_bounds__(1024) void scan2_kernel(const int* __restrict__ bsum,
                                                     int* __restrict__ boff,
                                                     int* __restrict__ row_ptr,
                                                     int nb, int N4, int E) {
    int tid = threadIdx.x;
    int lane = tid & 63;
    int w = tid >> 6;
    int v = (tid < nb) ? bsum[tid] : 0;
    int inc = wave_incl_scan(v, lane);
    __shared__ int wsum[16];
    if (lane == 63) wsum[w] = inc;
    __syncthreads();
    if (w == 0) {
        int s = (lane < 16) ? wsum[lane] : 0;
        int si = wave_incl_scan(s, lane);
        if (lane < 16) wsum[lane] = si - s;
    }
    __syncthreads();
    if (tid < nb) boff[tid] = inc - v + wsum[w];
    if (tid == 0) row_ptr[N4] = E;
}

__global__ void scan3_kernel(int* __restrict__ row_ptr, const int* __restrict__ boff, int N4) {
    int i = blockIdx.x * blockDim.x + threadIdx.x;
    if (i < N4) row_ptr[i] += boff[i >> 10];
}

// ---------------------------------------------------------------------------
// Fused MFMA GEMM body (verified core): t = x @ Wt.T,
// q = x @ Wp.T - t + (tb+pb), fp16 out. Now 64 rows/block (782 blocks ->
// ~3 blocks/CU for latency hiding). Wave owns 32 cols; all B frags in regs.
// C/D layout: col = lane&15, row = (lane>>4)*4 + reg.
// ---------------------------------------------------------------------------

static __device__ __forceinline__ void gemm_body(
        int bx,
        const _Float16* __restrict__ x16,
        const _Float16* __restrict__ wt, const _Float16* __restrict__ wp,
        const float* __restrict__ bias,
        _Float16* __restrict__ t16, _Float16* __restrict__ q16, int M) {
    int lane = threadIdx.x & 63;
    int l16 = lane & 15;
    int quad = lane >> 4;
    int cn0 = (threadIdx.x >> 6) * 32;

    f16x8 bt[2][4], bp[2][4];
    float biasv[2];
#pragma unroll
    for (int ct = 0; ct < 2; ++ct) {
        int col = cn0 + ct * 16 + l16;
        biasv[ct] = bias[col];
#pragma unroll
        for (int kk = 0; kk < 4; ++kk) {
            int k = kk * 32 + quad * 8;
            bt[ct][kk] = *(const f16x8*)(wt + (size_t)col * FEAT + k);
            bp[ct][kk] = *(const f16x8*)(wp + (size_t)col * FEAT + k);
        }
    }

    int rbase0 = bx * 64;
#pragma unroll 1
    for (int rs = 0; rs < 4; ++rs) {
        int rbase = rbase0 + rs * 16;
        int row = rbase + l16;
        int rowc = (row < M) ? row : (M - 1);
        f16x8 a[4];
#pragma unroll
        for (int kk = 0; kk < 4; ++kk)
            a[kk] = *(const f16x8*)(x16 + (size_t)rowc * FEAT + kk * 32 + quad * 8);

        f32x4 accT[2] = {{0.f, 0.f, 0.f, 0.f}, {0.f, 0.f, 0.f, 0.f}};
        f32x4 accP[2] = {{0.f, 0.f, 0.f, 0.f}, {0.f, 0.f, 0.f, 0.f}};
#pragma unroll
        for (int kk = 0; kk < 4; ++kk) {
#pragma unroll
            for (int ct = 0; ct < 2; ++ct) {
                accT[ct] = __builtin_amdgcn_mfma_f32_16x16x32_f16(a[kk], bt[ct][kk], accT[ct], 0, 0, 0);
                accP[ct] = __builtin_amdgcn_mfma_f32_16x16x32_f16(a[kk], bp[ct][kk], accP[ct], 0, 0, 0);
            }
        }
#pragma unroll
        for (int ct = 0; ct < 2; ++ct) {
            int col = cn0 + ct * 16 + l16;
#pragma unroll
            for (int r = 0; r < 4; ++r) {
                int ro = rbase + quad * 4 + r;
                if (ro < M) {
                    t16[(size_t)ro * FEAT + col] = (_Float16)accT[ct][r];
                    q16[(size_t)ro * FEAT + col] =
                        (_Float16)(accP[ct][r] - accT[ct][r] + biasv[ct]);
                }
            }
        }
    }
}

__global__ __launch_bounds__(256) void mfma_gemm_kernel(
        const _Float16* __restrict__ x16,
        const _Float16* __restrict__ wt, const _Float16* __restrict__ wp,
        const float* __restrict__ bias,
        _Float16* __restrict__ t16, _Float16* __restrict__ q16, int M) {
    gemm_body(blockIdx.x, x16, wt, wp, bias, t16, q16, M);
}

// Layer-0 GEMM fused with the CSR scatter (slab-bucketed key dst*4+slab).
__global__ __launch_bounds__(256) void fused0_kernel(
        const _Float16* __restrict__ x16,
        const _Float16* __restrict__ wt, const _Float16* __restrict__ wp,
        const float* __restrict__ bias,
        _Float16* __restrict__ t16, _Float16* __restrict__ q16, int M, int gb,
        const int* __restrict__ src, const int* __restrict__ dst,
        const int* __restrict__ row_ptr4, int* __restrict__ fill4,
        int* __restrict__ esrc, int E, int slab_size) {
    if ((int)blockIdx.x < gb) {
        gemm_body(blockIdx.x, x16, wt, wp, bias, t16, q16, M);
    } else {
        int e = (blockIdx.x - gb) * 256 + threadIdx.x;
        if (e < E) {
            int s = src[e];
            int key = dst[e] * SLABS + s / slab_size;
            int pos = row_ptr4[key] + atomicAdd(&fill4[key], 1);
            esrc[pos] = s;
        }
    }
}

// ---------------------------------------------------------------------------
// Aggregation + epilogue. One wave per node; lane = (g = edge slot, c =
// feature chunk of 8 fp16). Edge list is bucketed into 4 source-slabs
// (3.2 MB of t16 each, < 4 MB per-XCD L2); slabs are processed SEQUENTIALLY
// so co-resident waves gather from the same L2-resident slab.
// out = relu( max_e t[src_e] + q[i] ); edgeless nodes fall out naturally
// (m stays at -65504 -> relu gives 0).
// ---------------------------------------------------------------------------

static __device__ __forceinline__ f16x8 vmax8(f16x8 a, f16x8 b) {
#pragma unroll
    for (int i = 0; i < 8; ++i) a[i] = (a[i] > b[i]) ? a[i] : b[i];
    return a;
}

static __device__ __forceinline__ f16x8 shflxor8(f16x8 v, int mask) {
    union { f16x8 h; int i[4]; } u;
    u.h = v;
#pragma unroll
    for (int k = 0; k < 4; ++k) u.i[k] = __shfl_xor(u.i[k], mask, 64);
    return u.h;
}

__global__ __launch_bounds__(256) void agg_kernel(
        const _Float16* __restrict__ t16, const _Float16* __restrict__ q16,
        const int* __restrict__ row_ptr4, const int* __restrict__ esrc,
        float* __restrict__ outf, _Float16* __restrict__ ox, int N) {
    int wv = threadIdx.x >> 6;
    int lane = threadIdx.x & 63;
    int node = blockIdx.x * 4 + wv;
    if (node >= N) return;

    int g = lane >> 4;
    int c = lane & 15;

    const _Float16 NEGINF = (_Float16)(-65504.0f);
    f16x8 m;
#pragma unroll
    for (int i = 0; i < 8; ++i) m[i] = NEGINF;

#pragma unroll 1
    for (int s = 0; s < SLABS; ++s) {           // slab phases: L2 locality
        int beg = row_ptr4[4 * node + s];
        int end = row_ptr4[4 * node + s + 1];
        for (int base = beg; base < end; base += 64) {
            int n = end - base;
            if (n > 64) n = 64;
            int nm1 = n - 1;
            int li = (lane < n) ? lane : nm1;
            int myidx = esrc[base + li];        // one coalesced load
            for (int j = 0; j < n; j += 16) {   // 16 edges per group, 4 slots
                bool b1 = (j + 4) < n, b2 = (j + 8) < n, b3 = (j + 12) < n;
                int s0 = j + g;       if (s0 > nm1) s0 = nm1;
                f16x8 v0 = *(const f16x8*)(t16 + (size_t)__shfl(myidx, s0) * FEAT + c * 8);
                f16x8 v1, v2, v3;
                if (b1) {
                    int s1 = j + 4 + g;  if (s1 > nm1) s1 = nm1;
                    v1 = *(const f16x8*)(t16 + (size_t)__shfl(myidx, s1) * FEAT + c * 8);
                }
                if (b2) {
                    int s2 = j + 8 + g;  if (s2 > nm1) s2 = nm1;
                    v2 = *(const f16x8*)(t16 + (size_t)__shfl(myidx, s2) * FEAT + c * 8);
                }
                if (b3) {
                    int s3 = j + 12 + g; if (s3 > nm1) s3 = nm1;
                    v3 = *(const f16x8*)(t16 + (size_t)__shfl(myidx, s3) * FEAT + c * 8);
                }
                f16x8 acc = v0;
                if (b1) acc = vmax8(acc, v1);
                if (b2) acc = vmax8(acc, v2);
                if (b3) acc = vmax8(acc, v3);
                m = vmax8(m, acc);
            }
        }
    }

    // combine the 4 edge slots (butterfly over lane bits 4 and 5)
    m = vmax8(m, shflxor8(m, 16));
    m = vmax8(m, shflxor8(m, 32));

    // epilogue on slot-0 lanes (16 lanes x 8 features = full row)
    if (g == 0) {
        f16x8 qi = *(const f16x8*)(q16 + (size_t)node * FEAT + c * 8);
        float o[8];
#pragma unroll
        for (int i = 0; i < 8; ++i)
            o[i] = fmaxf((float)m[i] + (float)qi[i], 0.f);

        if (outf) {
            float4 o0 = make_float4(o[0], o[1], o[2], o[3]);
            float4 o1 = make_float4(o[4], o[5], o[6], o[7]);
            ((float4*)(outf + (size_t)node * FEAT + c * 8))[0] = o0;
            ((float4*)(outf + (size_t)node * FEAT + c * 8))[1] = o1;
        }
        if (ox) {
            f16x8 oh;
#pragma unroll
            for (int i = 0; i < 8; ++i) oh[i] = (_Float16)o[i];
            *(f16x8*)(ox + (size_t)node * FEAT + c * 8) = oh;
        }
    }
}

// ---------------------------------------------------------------------------

extern "C" void kernel_launch(void* const* d_in, const int* in_sizes, int n_in,
                              void* d_out, int out_size, void* d_ws, size_t ws_size,
                              hipStream_t stream) {
    const float* feats   = (const float*)d_in[0];
    const int*   src     = (const int*)d_in[1];
    const int*   dst     = (const int*)d_in[2];
    const float* theta_w = (const float*)d_in[3];
    const float* theta_b = (const float*)d_in[4];
    const float* phi_w   = (const float*)d_in[5];
    const float* phi_b   = (const float*)d_in[6];

    const int N = in_sizes[0] / FEAT;
    const int E = in_sizes[1];
    const int L = in_sizes[3] / (FEAT * FEAT);
    const int N4 = N * SLABS;
    const int slab_size = (N + SLABS - 1) / SLABS;

    char* ws = (char*)d_ws;
    size_t off = 0;
    auto alloc = [&](size_t bytes) -> void* {
        void* ptr = ws + off;
        off = (off + bytes + 255) & ~(size_t)255;
        return ptr;
    };
    _Float16* t16 = (_Float16*)alloc((size_t)N * FEAT * 2);
    _Float16* q16 = (_Float16*)alloc((size_t)N * FEAT * 2);
    _Float16* x16 = (_Float16*)alloc((size_t)N * FEAT * 2);
    _Float16* wt16 = (_Float16*)alloc((size_t)L * FEAT * FEAT * 2);
    _Float16* wp16 = (_Float16*)alloc((size_t)L * FEAT * FEAT * 2);
    float* bsum_b = (float*)alloc((size_t)L * FEAT * sizeof(float));
    int* deg4     = (int*)alloc((size_t)N4 * sizeof(int));
    int* fill4    = (int*)alloc((size_t)N4 * sizeof(int));
    int* row_ptr4 = (int*)alloc((size_t)(N4 + 1) * sizeof(int));
    int* esrc     = (int*)alloc((size_t)E * sizeof(int));
    int* bsum     = (int*)alloc(2048 * sizeof(int));
    int* boff     = (int*)alloc(2048 * sizeof(int));
    (void)ws_size;

    hipMemsetAsync(deg4, 0, (size_t)N4 * sizeof(int), stream);
    hipMemsetAsync(fill4, 0, (size_t)N4 * sizeof(int), stream);

    int eb = (E + 255) / 256;
    int wn = L * FEAT * FEAT;
    int wb = (wn + 255) / 256;
    int xn4 = N * FEAT / 4;
    int xb = (xn4 + 255) / 256;
    prep_kernel<<<eb + wb + xb, 256, 0, stream>>>(
        src, dst, deg4, E, slab_size,
        theta_w, phi_w, theta_b, phi_b, wt16, wp16, bsum_b, wn, L * FEAT,
        feats, x16, xn4, eb, wb);

    int nb = (N4 + 1023) >> 10;
    scan1_kernel<<<nb, 1024, 0, stream>>>(deg4, row_ptr4, bsum, N4);
    scan2_kernel<<<1, 1024, 0, stream>>>(bsum, boff, row_ptr4, nb, N4, E);
    scan3_kernel<<<(N4 + 255) / 256, 256, 0, stream>>>(row_ptr4, boff, N4);

    int gb = (N + 63) / 64;
    for (int l = 0; l < L; ++l) {
        if (l == 0) {
            fused0_kernel<<<gb + eb, 256, 0, stream>>>(
                x16, wt16, wp16, bsum_b, t16, q16, N, gb,
                src, dst, row_ptr4, fill4, esrc, E, slab_size);
        } else {
            mfma_gemm_kernel<<<gb, 256, 0, stream>>>(
                x16,
                wt16 + (size_t)l * FEAT * FEAT,
                wp16 + (size_t)l * FEAT * FEAT,
                bsum_b + (size_t)l * FEAT,
                t16, q16, N);
        }

        bool last = (l == L - 1);
        agg_kernel<<<(N + 3) / 4, 256, 0, stream>>>(
            t16, q16,
            row_ptr4, esrc,
            last ? (float*)d_out : nullptr,
            last ? nullptr : x16,   // in-place: x16 fully consumed before agg runs
            N);
    }
}

// Round 10
// 325.187 us; speedup vs baseline: 1.2411x; 1.2411x over previous
//
#include <hip/hip_runtime.h>

#define FEAT 128
#define SLABS 4

typedef __attribute__((ext_vector_type(8))) _Float16 f16x8;
typedef __attribute__((ext_vector_type(2))) _Float16 f16x2;
typedef __attribute__((ext_vector_type(4))) float f32x4;

static __device__ __forceinline__ int wave_incl_scan(int v, int lane) {
#pragma unroll
    for (int off = 1; off < 64; off <<= 1) {
        int u = __shfl_up(v, off, 64);
        if (lane >= off) v += u;
    }
    return v;
}

// ---------------------------------------------------------------------------
// Prep: histogram over (dst,slab) keys + weight/bias/feat converts, one
// dispatch partitioned by blockIdx (all three parts independent).
// ---------------------------------------------------------------------------

__global__ void prep_kernel(const int* __restrict__ src, const int* __restrict__ dst,
                            int* __restrict__ deg4, int E, int slab_size,
                            const float* __restrict__ tw, const float* __restrict__ pw,
                            const float* __restrict__ tb, const float* __restrict__ pb,
                            _Float16* __restrict__ wt, _Float16* __restrict__ wp,
                            float* __restrict__ bsum, int wn, int nbias,
                            const float* __restrict__ x, _Float16* __restrict__ x16, int xn4,
                            int hb, int wb) {
    int bid = blockIdx.x;
    if (bid < hb) {
        int e = bid * 256 + threadIdx.x;
        if (e < E) {
            int sl = src[e] / slab_size;
            atomicAdd(&deg4[dst[e] * SLABS + sl], 1);
        }
    } else if (bid < hb + wb) {
        int i = (bid - hb) * 256 + threadIdx.x;
        if (i < wn) { wt[i] = (_Float16)tw[i]; wp[i] = (_Float16)pw[i]; }
        if (i < nbias) bsum[i] = tb[i] + pb[i];
    } else {
        int i = (bid - hb - wb) * 256 + threadIdx.x;
        if (i < xn4) {
            float4 v = ((const float4*)x)[i];
            f16x2 a, b;
            a[0] = (_Float16)v.x; a[1] = (_Float16)v.y;
            b[0] = (_Float16)v.z; b[1] = (_Float16)v.w;
            ((f16x2*)x16)[i * 2] = a;
            ((f16x2*)x16)[i * 2 + 1] = b;
        }
    }
}

// ---------------------------------------------------------------------------
// 3-phase parallel scan over the 4N (dst,slab) degree array.
// ---------------------------------------------------------------------------

__global__ __launch_bounds__(1024) void scan1_kernel(const int* __restrict__ deg,
                                                     int* __restrict__ row_ptr,
                                                     int* __restrict__ bsum, int N4) {
    int i = blockIdx.x * 1024 + threadIdx.x;
    int lane = threadIdx.x & 63;
    int w = threadIdx.x >> 6;
    int v = (i < N4) ? deg[i] : 0;
    int inc = wave_incl_scan(v, lane);
    __shared__ int wsum[16];
    if (lane == 63) wsum[w] = inc;
    __syncthreads();
    if (w == 0) {
        int s = (lane < 16) ? wsum[lane] : 0;
        int si = wave_incl_scan(s, lane);
        if (lane < 16) wsum[lane] = si - s;
    }
    __syncthreads();
    int exc = inc - v + wsum[w];
    if (i < N4) row_ptr[i] = exc;
    if (threadIdx.x == 1023) bsum[blockIdx.x] = exc + v;
}

__global__ __launch_bounds__(1024) void scan2_kernel(const int* __restrict__ bsum,
                                                     int* __restrict__ boff,
                                                     int* __restrict__ row_ptr,
                                                     int nb, int N4, int E) {
    int tid = threadIdx.x;
    int lane = tid & 63;
    int w = tid >> 6;
    int v = (tid < nb) ? bsum[tid] : 0;
    int inc = wave_incl_scan(v, lane);
    __shared__ int wsum[16];
    if (lane == 63) wsum[w] = inc;
    __syncthreads();
    if (w == 0) {
        int s = (lane < 16) ? wsum[lane] : 0;
        int si = wave_incl_scan(s, lane);
        if (lane < 16) wsum[lane] = si - s;
    }
    __syncthreads();
    if (tid < nb) boff[tid] = inc - v + wsum[w];
    if (tid == 0) row_ptr[N4] = E;
}

__global__ void scan3_kernel(int* __restrict__ row_ptr, const int* __restrict__ boff, int N4) {
    int i = blockIdx.x * blockDim.x + threadIdx.x;
    if (i < N4) row_ptr[i] += boff[i >> 10];
}

// ---------------------------------------------------------------------------
// Fused MFMA GEMM body (round-8 verified, 128 rows/block): t = x @ Wt.T,
// q = x @ Wp.T - t + (tb+pb), fp16 out. Wave owns 32 cols; all B frags in
// regs. No LDS, no barriers. C/D layout: col = lane&15, row = (lane>>4)*4+reg.
// ---------------------------------------------------------------------------

static __device__ __forceinline__ void gemm_body(
        int bx,
        const _Float16* __restrict__ x16,
        const _Float16* __restrict__ wt, const _Float16* __restrict__ wp,
        const float* __restrict__ bias,
        _Float16* __restrict__ t16, _Float16* __restrict__ q16, int M) {
    int lane = threadIdx.x & 63;
    int l16 = lane & 15;
    int quad = lane >> 4;
    int cn0 = (threadIdx.x >> 6) * 32;

    f16x8 bt[2][4], bp[2][4];
    float biasv[2];
#pragma unroll
    for (int ct = 0; ct < 2; ++ct) {
        int col = cn0 + ct * 16 + l16;
        biasv[ct] = bias[col];
#pragma unroll
        for (int kk = 0; kk < 4; ++kk) {
            int k = kk * 32 + quad * 8;
            bt[ct][kk] = *(const f16x8*)(wt + (size_t)col * FEAT + k);
            bp[ct][kk] = *(const f16x8*)(wp + (size_t)col * FEAT + k);
        }
    }

    int rbase0 = bx * 128;
#pragma unroll 1
    for (int rs = 0; rs < 8; ++rs) {
        int rbase = rbase0 + rs * 16;
        int row = rbase + l16;
        int rowc = (row < M) ? row : (M - 1);
        f16x8 a[4];
#pragma unroll
        for (int kk = 0; kk < 4; ++kk)
            a[kk] = *(const f16x8*)(x16 + (size_t)rowc * FEAT + kk * 32 + quad * 8);

        f32x4 accT[2] = {{0.f, 0.f, 0.f, 0.f}, {0.f, 0.f, 0.f, 0.f}};
        f32x4 accP[2] = {{0.f, 0.f, 0.f, 0.f}, {0.f, 0.f, 0.f, 0.f}};
#pragma unroll
        for (int kk = 0; kk < 4; ++kk) {
#pragma unroll
            for (int ct = 0; ct < 2; ++ct) {
                accT[ct] = __builtin_amdgcn_mfma_f32_16x16x32_f16(a[kk], bt[ct][kk], accT[ct], 0, 0, 0);
                accP[ct] = __builtin_amdgcn_mfma_f32_16x16x32_f16(a[kk], bp[ct][kk], accP[ct], 0, 0, 0);
            }
        }
#pragma unroll
        for (int ct = 0; ct < 2; ++ct) {
            int col = cn0 + ct * 16 + l16;
#pragma unroll
            for (int r = 0; r < 4; ++r) {
                int ro = rbase + quad * 4 + r;
                if (ro < M) {
                    t16[(size_t)ro * FEAT + col] = (_Float16)accT[ct][r];
                    q16[(size_t)ro * FEAT + col] =
                        (_Float16)(accP[ct][r] - accT[ct][r] + biasv[ct]);
                }
            }
        }
    }
}

__global__ __launch_bounds__(256) void mfma_gemm_kernel(
        const _Float16* __restrict__ x16,
        const _Float16* __restrict__ wt, const _Float16* __restrict__ wp,
        const float* __restrict__ bias,
        _Float16* __restrict__ t16, _Float16* __restrict__ q16, int M) {
    gemm_body(blockIdx.x, x16, wt, wp, bias, t16, q16, M);
}

// Layer-0 GEMM fused with the CSR scatter (slab-bucketed key dst*4+slab).
__global__ __launch_bounds__(256) void fused0_kernel(
        const _Float16* __restrict__ x16,
        const _Float16* __restrict__ wt, const _Float16* __restrict__ wp,
        const float* __restrict__ bias,
        _Float16* __restrict__ t16, _Float16* __restrict__ q16, int M, int gb,
        const int* __restrict__ src, const int* __restrict__ dst,
        const int* __restrict__ row_ptr4, int* __restrict__ fill4,
        int* __restrict__ esrc, int E, int slab_size) {
    if ((int)blockIdx.x < gb) {
        gemm_body(blockIdx.x, x16, wt, wp, bias, t16, q16, M);
    } else {
        int e = (blockIdx.x - gb) * 256 + threadIdx.x;
        if (e < E) {
            int s = src[e];
            int key = dst[e] * SLABS + s / slab_size;
            int pos = row_ptr4[key] + atomicAdd(&fill4[key], 1);
            esrc[pos] = s;
        }
    }
}

// ---------------------------------------------------------------------------
// Aggregation + epilogue. One wave = 4 CONSECUTIVE NODES, one per 16-lane
// slot (g = lane>>4 -> node node0+g, c = lane&15 -> feature chunk of 8).
// Each slot gathers its own node's slab-s segment: one f16x8 load carries up
// to 4 rows (one per slot) with NO starvation even for short segments.
// Slabs (3.2 MB of t16 < 4 MB/XCD L2) processed sequentially -> co-resident
// waves hit the L2-resident slab. Control flow wave-uniform (cntmax reduce);
// loads/maxes predicated per slot. Inner k unrolled x4, 4 accumulators.
// out = relu( max_e t[src_e] + q[i] ); edgeless -> m=-65504 -> relu -> 0.
// ---------------------------------------------------------------------------

static __device__ __forceinline__ f16x8 vmax8(f16x8 a, f16x8 b) {
#pragma unroll
    for (int i = 0; i < 8; ++i) a[i] = (a[i] > b[i]) ? a[i] : b[i];
    return a;
}

__global__ __launch_bounds__(256) void agg_kernel(
        const _Float16* __restrict__ t16, const _Float16* __restrict__ q16,
        const int* __restrict__ row_ptr4, const int* __restrict__ esrc,
        float* __restrict__ outf, _Float16* __restrict__ ox, int N, int E) {
    int wv = threadIdx.x >> 6;
    int lane = threadIdx.x & 63;
    int node0 = (blockIdx.x * 4 + wv) * 4;
    if (node0 >= N) return;

    int g = lane >> 4;
    int c = lane & 15;
    int nodeg = node0 + g;
    bool nvalid = nodeg < N;

    // row_ptr4[4*node0 .. 4*node0+16] via one coalesced 17-lane load
    int rpmax = SLABS * N;
    int rpidx = SLABS * node0 + (lane < 17 ? lane : 16);
    if (rpidx > rpmax) rpidx = rpmax;
    int rp = row_ptr4[rpidx];

    const _Float16 NEGINF = (_Float16)(-65504.0f);
    f16x8 m0, m1, m2, m3;
#pragma unroll
    for (int i = 0; i < 8; ++i) { m0[i] = NEGINF; m1[i] = NEGINF; m2[i] = NEGINF; m3[i] = NEGINF; }

#pragma unroll 1
    for (int s = 0; s < SLABS; ++s) {
        int beg = __shfl(rp, SLABS * g + s);
        int end = __shfl(rp, SLABS * g + s + 1);
        int cnt = end - beg;                       // uniform within a slot
        // wave-uniform trip count: max cnt over the 4 slots
        int cm = cnt;
        cm = max(cm, __shfl_xor(cm, 16, 64));
        cm = max(cm, __shfl_xor(cm, 32, 64));

        for (int base = 0; base < cm; base += 16) {
            int rem = cnt - base;                  // per-slot, may be <= 0
            int off = (c < rem) ? c : (rem > 0 ? rem - 1 : 0);
            int a = beg + base + off;
            if (a < 0) a = 0;
            if (a >= E) a = E - 1;
            int myidx = esrc[a];                   // slot-coalesced (64 B/slot)
            int kend = cm - base; if (kend > 16) kend = 16;
            int k = 0;
            for (; k + 4 <= kend; k += 4) {        // 4 independent gathers/slot
                int i0 = __shfl(myidx, 16 * g + k);
                int i1 = __shfl(myidx, 16 * g + k + 1);
                int i2 = __shfl(myidx, 16 * g + k + 2);
                int i3 = __shfl(myidx, 16 * g + k + 3);
                bool p0 = (k < rem), p1 = (k + 1 < rem), p2 = (k + 2 < rem), p3 = (k + 3 < rem);
                f16x8 v0, v1, v2, v3;
                if (p0) v0 = *(const f16x8*)(t16 + (size_t)i0 * FEAT + c * 8);
                if (p1) v1 = *(const f16x8*)(t16 + (size_t)i1 * FEAT + c * 8);
                if (p2) v2 = *(const f16x8*)(t16 + (size_t)i2 * FEAT + c * 8);
                if (p3) v3 = *(const f16x8*)(t16 + (size_t)i3 * FEAT + c * 8);
                if (p0) m0 = vmax8(m0, v0);
                if (p1) m1 = vmax8(m1, v1);
                if (p2) m2 = vmax8(m2, v2);
                if (p3) m3 = vmax8(m3, v3);
            }
            for (; k < kend; ++k) {
                int idx = __shfl(myidx, 16 * g + k);
                if (k < rem) {
                    f16x8 v = *(const f16x8*)(t16 + (size_t)idx * FEAT + c * 8);
                    m0 = vmax8(m0, v);
                }
            }
        }
    }

    f16x8 m = vmax8(vmax8(m0, m1), vmax8(m2, m3));

    // epilogue: every slot writes its own node's row (16 lanes x 8 features)
    if (nvalid) {
        f16x8 qi = *(const f16x8*)(q16 + (size_t)nodeg * FEAT + c * 8);
        float o[8];
#pragma unroll
        for (int i = 0; i < 8; ++i)
            o[i] = fmaxf((float)m[i] + (float)qi[i], 0.f);

        if (outf) {
            float4 o0 = make_float4(o[0], o[1], o[2], o[3]);
            float4 o1 = make_float4(o[4], o[5], o[6], o[7]);
            ((float4*)(outf + (size_t)nodeg * FEAT + c * 8))[0] = o0;
            ((float4*)(outf + (size_t)nodeg * FEAT + c * 8))[1] = o1;
        }
        if (ox) {
            f16x8 oh;
#pragma unroll
            for (int i = 0; i < 8; ++i) oh[i] = (_Float16)o[i];
            *(f16x8*)(ox + (size_t)nodeg * FEAT + c * 8) = oh;
        }
    }
}

// ---------------------------------------------------------------------------

extern "C" void kernel_launch(void* const* d_in, const int* in_sizes, int n_in,
                              void* d_out, int out_size, void* d_ws, size_t ws_size,
                              hipStream_t stream) {
    const float* feats   = (const float*)d_in[0];
    const int*   src     = (const int*)d_in[1];
    const int*   dst     = (const int*)d_in[2];
    const float* theta_w = (const float*)d_in[3];
    const float* theta_b = (const float*)d_in[4];
    const float* phi_w   = (const float*)d_in[5];
    const float* phi_b   = (const float*)d_in[6];

    const int N = in_sizes[0] / FEAT;
    const int E = in_sizes[1];
    const int L = in_sizes[3] / (FEAT * FEAT);
    const int N4 = N * SLABS;
    const int slab_size = (N + SLABS - 1) / SLABS;

    char* ws = (char*)d_ws;
    size_t off = 0;
    auto alloc = [&](size_t bytes) -> void* {
        void* ptr = ws + off;
        off = (off + bytes + 255) & ~(size_t)255;
        return ptr;
    };
    _Float16* t16 = (_Float16*)alloc((size_t)N * FEAT * 2);
    _Float16* q16 = (_Float16*)alloc((size_t)N * FEAT * 2);
    _Float16* x16 = (_Float16*)alloc((size_t)N * FEAT * 2);
    _Float16* wt16 = (_Float16*)alloc((size_t)L * FEAT * FEAT * 2);
    _Float16* wp16 = (_Float16*)alloc((size_t)L * FEAT * FEAT * 2);
    float* bsum_b = (float*)alloc((size_t)L * FEAT * sizeof(float));
    int* deg4     = (int*)alloc((size_t)N4 * sizeof(int));
    int* fill4    = (int*)alloc((size_t)N4 * sizeof(int));
    int* row_ptr4 = (int*)alloc((size_t)(N4 + 1) * sizeof(int));
    int* esrc     = (int*)alloc((size_t)E * sizeof(int));
    int* bsum     = (int*)alloc(2048 * sizeof(int));
    int* boff     = (int*)alloc(2048 * sizeof(int));
    (void)ws_size;

    hipMemsetAsync(deg4, 0, (size_t)N4 * sizeof(int), stream);
    hipMemsetAsync(fill4, 0, (size_t)N4 * sizeof(int), stream);

    int eb = (E + 255) / 256;
    int wn = L * FEAT * FEAT;
    int wb = (wn + 255) / 256;
    int xn4 = N * FEAT / 4;
    int xb = (xn4 + 255) / 256;
    prep_kernel<<<eb + wb + xb, 256, 0, stream>>>(
        src, dst, deg4, E, slab_size,
        theta_w, phi_w, theta_b, phi_b, wt16, wp16, bsum_b, wn, L * FEAT,
        feats, x16, xn4, eb, wb);

    int nb = (N4 + 1023) >> 10;
    scan1_kernel<<<nb, 1024, 0, stream>>>(deg4, row_ptr4, bsum, N4);
    scan2_kernel<<<1, 1024, 0, stream>>>(bsum, boff, row_ptr4, nb, N4, E);
    scan3_kernel<<<(N4 + 255) / 256, 256, 0, stream>>>(row_ptr4, boff, N4);

    int gb = (N + 127) / 128;
    int ab = (N + 15) / 16;   // 4 waves x 4 nodes per block
    for (int l = 0; l < L; ++l) {
        if (l == 0) {
            fused0_kernel<<<gb + eb, 256, 0, stream>>>(
                x16, wt16, wp16, bsum_b, t16, q16, N, gb,
                src, dst, row_ptr4, fill4, esrc, E, slab_size);
        } else {
            mfma_gemm_kernel<<<gb, 256, 0, stream>>>(
                x16,
                wt16 + (size_t)l * FEAT * FEAT,
                wp16 + (size_t)l * FEAT * FEAT,
                bsum_b + (size_t)l * FEAT,
                t16, q16, N);
        }

        bool last = (l == L - 1);
        agg_kernel<<<ab, 256, 0, stream>>>(
            t16, q16,
            row_ptr4, esrc,
            last ? (float*)d_out : nullptr,
            last ? nullptr : x16,   // in-place: x16 fully consumed before agg runs
            N, E);
    }
}